// Round 1
// baseline (1837.789 us; speedup 1.0000x reference)
//
#include <hip/hip_runtime.h>

#define BBATCH 16384
#define NSEQ   50
#define EDIM   100
#define TDIM   8
#define LDIM   5000
#define PPAIR  4950
#define BNROWS (BBATCH*NSEQ)   /* 819200 */
#define EPSF   1e-5f
#define PADF   -4294967296.0f

// ---------------------------------------------------------------------------
// K0: pair prep — vvp[p] = <v_i, v_j>, iu[p]=i, ju[p]=j  (row-major i<j order)
// ---------------------------------------------------------------------------
__global__ __launch_bounds__(128) void k_prep(const float* __restrict__ v,
                                              float* __restrict__ vvp,
                                              int* __restrict__ iu,
                                              int* __restrict__ ju) {
  int i = blockIdx.x;                 // 0..99
  int jcount = EDIM - 1 - i;
  int pstart = i * (2 * EDIM - 1 - i) / 2;
  float v0 = v[i*4+0], v1 = v[i*4+1], v2 = v[i*4+2], v3 = v[i*4+3];
  for (int jj = threadIdx.x; jj < jcount; jj += blockDim.x) {
    int j = i + 1 + jj;
    int p = pstart + jj;
    vvp[p] = v0*v[j*4+0] + v1*v[j*4+1] + v2*v[j*4+2] + v3*v[j*4+3];
    iu[p] = i; ju[p] = j;
  }
}

// ---------------------------------------------------------------------------
// K1: per (b,n) row: sign, hq1 = relu(x@W1+b1)@q1 (pre-BN), hq2; partial BN3
// sums (sum h, sum h^2 per n, per pool) -> part[block][200]
// ---------------------------------------------------------------------------
__global__ __launch_bounds__(256) void k_attn1(const float* __restrict__ x,
    const float* __restrict__ W1, const float* __restrict__ b1, const float* __restrict__ q1,
    const float* __restrict__ W3, const float* __restrict__ b3, const float* __restrict__ q2,
    float* __restrict__ sgn, float* __restrict__ hq1o, float* __restrict__ hq2o,
    float* __restrict__ part) {
  __shared__ float4 W1s[200];   // [e][t0..3],[e][t4..7]
  __shared__ float4 W3s[200];
  __shared__ float  Sl[200];    // S1[50] Q1[50] S2[50] Q2[50]
  __shared__ float  b1s[8], q1s[8], b3s[8], q2s[8];
  int tid = threadIdx.x;
  for (int idx = tid; idx < 200; idx += 256) {
    W1s[idx] = ((const float4*)W1)[idx];
    W3s[idx] = ((const float4*)W3)[idx];
    Sl[idx] = 0.f;
  }
  if (tid < 8) { b1s[tid]=b1[tid]; q1s[tid]=q1[tid]; b3s[tid]=b3[tid]; q2s[tid]=q2[tid]; }
  __syncthreads();

  const long stride = 1024L * 256L;
  for (long r = (long)blockIdx.x*256 + tid; r < BNROWS; r += stride) {
    const float4* xr = (const float4*)(x + r*100);
    float a1[8] = {0,0,0,0,0,0,0,0};
    float a2[8] = {0,0,0,0,0,0,0,0};
    float asum = 0.f;
    for (int e4 = 0; e4 < 25; ++e4) {
      float4 xv = xr[e4];
      float xe[4] = {xv.x, xv.y, xv.z, xv.w};
      #pragma unroll
      for (int u = 0; u < 4; ++u) {
        float xx = xe[u];
        asum += fabsf(xx);
        int e = e4*4 + u;
        float4 wa = W1s[2*e], wb = W1s[2*e+1];
        float wv1[8] = {wa.x,wa.y,wa.z,wa.w,wb.x,wb.y,wb.z,wb.w};
        #pragma unroll
        for (int t = 0; t < 8; ++t) a1[t] = fmaf(xx, wv1[t], a1[t]);
        float4 wc = W3s[2*e], wd = W3s[2*e+1];
        float wv2[8] = {wc.x,wc.y,wc.z,wc.w,wd.x,wd.y,wd.z,wd.w};
        #pragma unroll
        for (int t = 0; t < 8; ++t) a2[t] = fmaf(xx, wv2[t], a2[t]);
      }
    }
    float hq1v=0, s1=0, qq1=0, hq2v=0, s2=0, qq2=0;
    #pragma unroll
    for (int t = 0; t < 8; ++t) {
      float h1 = fmaxf(a1[t] + b1s[t], 0.f);
      hq1v = fmaf(h1, q1s[t], hq1v); s1 += h1; qq1 = fmaf(h1, h1, qq1);
      float h2 = fmaxf(a2[t] + b3s[t], 0.f);
      hq2v = fmaf(h2, q2s[t], hq2v); s2 += h2; qq2 = fmaf(h2, h2, qq2);
    }
    sgn[r]  = (asum != 0.f) ? 1.f : 0.f;
    hq1o[r] = hq1v;
    hq2o[r] = hq2v;
    int n = (int)(r % 50);
    atomicAdd(&Sl[n],       s1);
    atomicAdd(&Sl[50 + n],  qq1);
    atomicAdd(&Sl[100 + n], s2);
    atomicAdd(&Sl[150 + n], qq2);
  }
  __syncthreads();
  for (int idx = tid; idx < 200; idx += 256)
    part[(long)blockIdx.x*200 + idx] = Sl[idx];
}

// K1b: reduce part[1024][200] -> stats[0..199]
__global__ __launch_bounds__(256) void k_red(const float* __restrict__ part,
                                             float* __restrict__ stats) {
  int s = blockIdx.x;          // 0..199
  float acc = 0.f;
  for (int i = threadIdx.x; i < 1024; i += 256) acc += part[(long)i*200 + s];
  #pragma unroll
  for (int off = 32; off > 0; off >>= 1) acc += __shfl_down(acc, off, 64);
  __shared__ float red[4];
  if ((threadIdx.x & 63) == 0) red[threadIdx.x >> 6] = acc;
  __syncthreads();
  if (threadIdx.x == 0) stats[s] = red[0] + red[1] + red[2] + red[3];
}

// ---------------------------------------------------------------------------
// K2: per-b masked softmax (via BN affine on hq) + attention pooling
// pcat[b][0..99]=p1, [100..199]=p2
// ---------------------------------------------------------------------------
__global__ __launch_bounds__(128) void k_pool(const float* __restrict__ x,
    const float* __restrict__ sgn, const float* __restrict__ hq1, const float* __restrict__ hq2,
    const float* __restrict__ stats, const float* __restrict__ q1, const float* __restrict__ q2,
    const float* __restrict__ bn1g, const float* __restrict__ bn1b,
    float* __restrict__ pcat) {
  __shared__ float xs[50][100];
  __shared__ float a1s[50], a2s[50];
  long b = blockIdx.x;
  for (int idx = threadIdx.x; idx < 5000; idx += 128)
    xs[idx/100][idx%100] = x[b*5000 + idx];

  int w = threadIdx.x >> 6, lane = threadIdx.x & 63;
  const float* qq = w ? q2 : q1;
  const float* hq = w ? hq2 : hq1;
  const float* Sb = stats + (w ? 100 : 0);
  const float* Qb = stats + (w ? 150 : 50);
  float Qs = 0.f;
  #pragma unroll
  for (int t = 0; t < 8; ++t) Qs += qq[t];
  float s = -3.0e38f;
  if (lane < 50) {
    float m   = Sb[lane] * (1.f/131072.f);
    float var = Qb[lane] * (1.f/131072.f) - m*m;
    float inv = rsqrtf(var + EPSF);
    float A   = inv * bn1g[lane];
    float Bc  = (bn1b[lane] - m*A) * Qs;
    s = fmaf(A, hq[b*50 + lane], Bc);
    if (sgn[b*50 + lane] == 0.f) s = PADF;
  }
  float mx = s;
  #pragma unroll
  for (int off = 32; off > 0; off >>= 1) mx = fmaxf(mx, __shfl_down(mx, off, 64));
  mx = __shfl(mx, 0, 64);
  float ev = (lane < 50) ? expf(s - mx) : 0.f;
  float sm = ev;
  #pragma unroll
  for (int off = 32; off > 0; off >>= 1) sm += __shfl_down(sm, off, 64);
  sm = __shfl(sm, 0, 64);
  if (lane < 50) (w ? a2s : a1s)[lane] = ev / sm;
  __syncthreads();

  if (threadIdx.x < 100) {
    int e = threadIdx.x;
    float p1 = 0.f, p2 = 0.f;
    #pragma unroll 5
    for (int n = 0; n < 50; ++n) {
      float xv = xs[n][e];
      p1 = fmaf(xv, a1s[n], p1);
      p2 = fmaf(xv, a2s[n], p2);
    }
    pcat[b*200 + e]       = p1;
    pcat[b*200 + 100 + e] = p2;
  }
}

// ---------------------------------------------------------------------------
// K3: z5 = pcat @ W5 + b5   (W5 [200][100] staged in LDS in two 40KB halves)
// ---------------------------------------------------------------------------
__global__ __launch_bounds__(256) void k_z5(const float* __restrict__ pcat,
    const float* __restrict__ W5, const float* __restrict__ b5, float* __restrict__ z5) {
  __shared__ float Ws[10000];
  int tid = threadIdx.x;
  int rl = tid & 63, eg = tid >> 6;
  long r = (long)blockIdx.x*64 + rl;
  const float* pr = pcat + r*200;
  float acc[25] = {};
  for (int half = 0; half < 2; ++half) {
    __syncthreads();
    for (int idx = tid; idx < 10000; idx += 256) Ws[idx] = W5[half*10000 + idx];
    __syncthreads();
    const float* ph = pr + half*100;
    for (int k = 0; k < 100; ++k) {
      float vv = ph[k];
      #pragma unroll
      for (int j = 0; j < 25; ++j) acc[j] = fmaf(vv, Ws[k*100 + eg*25 + j], acc[j]);
    }
  }
  int c0 = eg*25;
  for (int j = 0; j < 25; ++j) z5[r*100 + c0 + j] = acc[j] + b5[c0 + j];
}

// column stats (sum, sumsq) of a [16384][100] array, 64 rows per block
__global__ __launch_bounds__(128) void k_colstats(const float* __restrict__ a,
                                                  float* __restrict__ S, float* __restrict__ Q) {
  int e = threadIdx.x;
  if (e >= 100) return;
  long r0 = (long)blockIdx.x * 64;
  float s = 0.f, q = 0.f;
  for (int i = 0; i < 64; ++i) {
    float vv = a[(r0 + i)*100 + e];
    s += vv; q = fmaf(vv, vv, q);
  }
  atomicAdd(&S[e], s);
  atomicAdd(&Q[e], q);
}

// ---------------------------------------------------------------------------
// K4a: z6 = bn(z5) @ W6 + b6
// ---------------------------------------------------------------------------
__global__ __launch_bounds__(256) void k_z6(const float* __restrict__ z5,
    const float* __restrict__ S5, const float* __restrict__ Q5,
    const float* __restrict__ g, const float* __restrict__ be,
    const float* __restrict__ W6, const float* __restrict__ b6, float* __restrict__ z6) {
  __shared__ float Ws[10000];
  __shared__ float A5s[100], B5s[100];
  int tid = threadIdx.x;
  if (tid < 100) {
    float m   = S5[tid] * (1.f/16384.f);
    float var = Q5[tid] * (1.f/16384.f) - m*m;
    float inv = rsqrtf(var + EPSF);
    float A = inv * g[tid];
    A5s[tid] = A; B5s[tid] = be[tid] - m*A;
  }
  for (int idx = tid; idx < 10000; idx += 256) Ws[idx] = W6[idx];
  __syncthreads();
  int rl = tid & 63, eg = tid >> 6;
  long r = (long)blockIdx.x*64 + rl;
  float acc[25] = {};
  for (int k = 0; k < 100; ++k) {
    float vv = fmaf(z5[r*100 + k], A5s[k], B5s[k]);
    #pragma unroll
    for (int j = 0; j < 25; ++j) acc[j] = fmaf(vv, Ws[k*100 + eg*25 + j], acc[j]);
  }
  int c0 = eg*25;
  for (int j = 0; j < 25; ++j) z6[r*100 + c0 + j] = acc[j] + b6[c0 + j];
}

// ---------------------------------------------------------------------------
// K4: z7_part = cross(bn(z5)) @ (VV ⊙ W7)   — split-K=2, pairs generated in LDS
// tile: 64 rows x 128 cols (100 valid), 256 thr, per-thread 8x4
// ---------------------------------------------------------------------------
__global__ __launch_bounds__(256) void k_cross(const float* __restrict__ z5,
    const float* __restrict__ S5, const float* __restrict__ Q5,
    const float* __restrict__ g, const float* __restrict__ be,
    const float* __restrict__ W7, const float* __restrict__ vvp,
    const int* __restrict__ iu, const int* __restrict__ ju,
    float* __restrict__ outa, float* __restrict__ outb) {
  __shared__ float h5s[64][128];
  __shared__ __align__(16) float crossT[32][64];
  __shared__ __align__(16) float W7c[32][128];
  __shared__ float A5s[100], B5s[100];
  int tid = threadIdx.x;
  int rb = blockIdx.x & 255;
  int kb = blockIdx.x >> 8;
  long r0 = (long)rb * 64;
  float* outp = kb ? outb : outa;
  int p0 = kb * 2475, pend = p0 + 2475;

  if (tid < 100) {
    float m   = S5[tid] * (1.f/16384.f);
    float var = Q5[tid] * (1.f/16384.f) - m*m;
    float inv = rsqrtf(var + EPSF);
    float A = inv * g[tid];
    A5s[tid] = A; B5s[tid] = be[tid] - m*A;
  }
  __syncthreads();
  for (int idx = tid; idx < 64*128; idx += 256) {
    int r = idx >> 7, c = idx & 127;
    h5s[r][c] = (c < 100) ? fmaf(z5[(r0 + r)*100 + c], A5s[c], B5s[c]) : 0.f;
  }

  float acc[8][4] = {};
  int tx = tid & 31, ty = tid >> 5;
  int genp = tid >> 3, genr = (tid & 7) * 8;

  for (int pc = 0; pc < 78; ++pc) {
    int pbase = p0 + pc*32;
    __syncthreads();   // previous chunk fully consumed
    for (int idx = tid; idx < 32*128; idx += 256) {
      int pl = idx >> 7, c = idx & 127;
      int p = pbase + pl;
      W7c[pl][c] = (c < 100 && p < pend) ? W7[(long)p*100 + c] : 0.f;
    }
    {
      int p = pbase + genp; if (p >= pend) p = pend - 1;
      int i = iu[p], j = ju[p];
      float vv = vvp[p];
      float4 c0v, c1v;
      c0v.x = h5s[genr+0][i]*h5s[genr+0][j]*vv;
      c0v.y = h5s[genr+1][i]*h5s[genr+1][j]*vv;
      c0v.z = h5s[genr+2][i]*h5s[genr+2][j]*vv;
      c0v.w = h5s[genr+3][i]*h5s[genr+3][j]*vv;
      c1v.x = h5s[genr+4][i]*h5s[genr+4][j]*vv;
      c1v.y = h5s[genr+5][i]*h5s[genr+5][j]*vv;
      c1v.z = h5s[genr+6][i]*h5s[genr+6][j]*vv;
      c1v.w = h5s[genr+7][i]*h5s[genr+7][j]*vv;
      *(float4*)&crossT[genp][genr]     = c0v;
      *(float4*)&crossT[genp][genr + 4] = c1v;
    }
    __syncthreads();
    #pragma unroll 4
    for (int pl = 0; pl < 32; ++pl) {
      float4 a0 = *(const float4*)&crossT[pl][ty*8];
      float4 a1 = *(const float4*)&crossT[pl][ty*8 + 4];
      float4 wv = *(const float4*)&W7c[pl][tx*4];
      float av8[8] = {a0.x,a0.y,a0.z,a0.w,a1.x,a1.y,a1.z,a1.w};
      float wv4[4] = {wv.x,wv.y,wv.z,wv.w};
      #pragma unroll
      for (int i2 = 0; i2 < 8; ++i2)
        #pragma unroll
        for (int j2 = 0; j2 < 4; ++j2)
          acc[i2][j2] = fmaf(av8[i2], wv4[j2], acc[i2][j2]);
    }
  }
  if (tx < 25) {
    int c = tx*4;
    #pragma unroll
    for (int i2 = 0; i2 < 8; ++i2) {
      float4 o = make_float4(acc[i2][0], acc[i2][1], acc[i2][2], acc[i2][3]);
      *(float4*)&outp[(r0 + ty*8 + i2)*100 + c] = o;
    }
  }
}

// combine split-K halves + b7, and produce z7 column stats
__global__ __launch_bounds__(128) void k_comb7(float* __restrict__ z7,
    const float* __restrict__ z7b, const float* __restrict__ b7,
    float* __restrict__ S, float* __restrict__ Q) {
  int e = threadIdx.x;
  if (e >= 100) return;
  long r0 = (long)blockIdx.x * 64;
  float bb = b7[e];
  float s = 0.f, q = 0.f;
  for (int i = 0; i < 64; ++i) {
    long off = (r0 + i)*100 + e;
    float vv = z7[off] + z7b[off] + bb;
    z7[off] = vv;
    s += vv; q = fmaf(vv, vv, q);
  }
  atomicAdd(&S[e], s);
  atomicAdd(&Q[e], q);
}

// ---------------------------------------------------------------------------
// K5: u = [bn(z6), bn(z7)] @ W8 + b8 ; h8 = LN(u)
// ---------------------------------------------------------------------------
__global__ __launch_bounds__(256) void k_h8(const float* __restrict__ z6,
    const float* __restrict__ z7,
    const float* __restrict__ S6, const float* __restrict__ Q6,
    const float* __restrict__ S7, const float* __restrict__ Q7,
    const float* __restrict__ g, const float* __restrict__ be,
    const float* __restrict__ W8, const float* __restrict__ b8,
    const float* __restrict__ lng, const float* __restrict__ lnb,
    float* __restrict__ h8) {
  __shared__ float Ws[10000];            // reused as us[64][102] afterwards
  __shared__ float A6s[100], B6s[100], A7s[100], B7s[100];
  int tid = threadIdx.x;
  if (tid < 100) {
    float m   = S6[tid] * (1.f/16384.f);
    float var = Q6[tid] * (1.f/16384.f) - m*m;
    float inv = rsqrtf(var + EPSF);
    float A = inv * g[tid];
    A6s[tid] = A; B6s[tid] = be[tid] - m*A;
  } else if (tid < 200) {
    int e = tid - 100;
    float m   = S7[e] * (1.f/16384.f);
    float var = Q7[e] * (1.f/16384.f) - m*m;
    float inv = rsqrtf(var + EPSF);
    float A = inv * g[e];
    A7s[e] = A; B7s[e] = be[e] - m*A;
  }
  int rl = tid & 63, eg = tid >> 6;
  long r = (long)blockIdx.x*64 + rl;
  float acc[25] = {};
  for (int half = 0; half < 2; ++half) {
    __syncthreads();
    for (int idx = tid; idx < 10000; idx += 256) Ws[idx] = W8[half*10000 + idx];
    __syncthreads();
    const float* zin = half ? z7 : z6;
    const float* As  = half ? A7s : A6s;
    const float* Bs  = half ? B7s : B6s;
    for (int k = 0; k < 100; ++k) {
      float vv = fmaf(zin[r*100 + k], As[k], Bs[k]);
      #pragma unroll
      for (int j = 0; j < 25; ++j) acc[j] = fmaf(vv, Ws[k*100 + eg*25 + j], acc[j]);
    }
  }
  __syncthreads();
  float* us = Ws;                        // [64][102]
  int c0 = eg*25;
  for (int j = 0; j < 25; ++j) us[rl*102 + c0 + j] = acc[j] + b8[c0 + j];
  __syncthreads();
  if (eg == 0) {
    float s = 0.f, q = 0.f;
    for (int e = 0; e < 100; ++e) { float vv = us[rl*102 + e]; s += vv; q = fmaf(vv, vv, q); }
    float m = s * 0.01f;
    float var = q * 0.01f - m*m;
    us[rl*102 + 100] = m;
    us[rl*102 + 101] = rsqrtf(var + EPSF);
  }
  __syncthreads();
  float m = us[rl*102 + 100], inv = us[rl*102 + 101];
  for (int j = 0; j < 25; ++j) {
    int e = c0 + j;
    h8[r*100 + e] = (us[rl*102 + e] - m) * inv * lng[e] + lnb[e];
  }
}

// ---------------------------------------------------------------------------
// K6: out = h8 @ label_emb   [16384,100]@[100,5000]
// tile 64 rows x 128 cols; A transposed in LDS; B streamed from L2
// ---------------------------------------------------------------------------
__global__ __launch_bounds__(256) void k_out(const float* __restrict__ h8,
                                             const float* __restrict__ lab,
                                             float* __restrict__ out) {
  __shared__ __align__(16) float As[100*68];
  int tid = threadIdx.x;
  int bc = blockIdx.x % 40;
  long br = blockIdx.x / 40;
  long r0 = br * 64;
  int c0 = bc * 128;
  for (int idx = tid; idx < 6400; idx += 256) {
    int r = idx / 100, k = idx % 100;
    As[k*68 + r] = h8[(r0 + r)*100 + k];
  }
  __syncthreads();
  int tx = tid & 31, ty = tid >> 5;
  int cc = c0 + tx*4;
  bool cok = (cc < LDIM);
  float acc[8][4] = {};
  #pragma unroll 2
  for (int k = 0; k < 100; ++k) {
    float4 a0 = *(const float4*)&As[k*68 + ty*8];
    float4 a1 = *(const float4*)&As[k*68 + ty*8 + 4];
    float4 bv = cok ? *(const float4*)&lab[(long)k*LDIM + cc]
                    : make_float4(0.f, 0.f, 0.f, 0.f);
    float av8[8] = {a0.x,a0.y,a0.z,a0.w,a1.x,a1.y,a1.z,a1.w};
    float bv4[4] = {bv.x,bv.y,bv.z,bv.w};
    #pragma unroll
    for (int i2 = 0; i2 < 8; ++i2)
      #pragma unroll
      for (int j2 = 0; j2 < 4; ++j2)
        acc[i2][j2] = fmaf(av8[i2], bv4[j2], acc[i2][j2]);
  }
  if (cok) {
    #pragma unroll
    for (int i2 = 0; i2 < 8; ++i2) {
      float4 o = make_float4(acc[i2][0], acc[i2][1], acc[i2][2], acc[i2][3]);
      *(float4*)&out[(r0 + ty*8 + i2)*LDIM + cc] = o;
    }
  }
}

// ---------------------------------------------------------------------------
extern "C" void kernel_launch(void* const* d_in, const int* in_sizes, int n_in,
                              void* d_out, int out_size, void* d_ws, size_t ws_size,
                              hipStream_t stream) {
  const float* x    = (const float*)d_in[0];
  const float* W1   = (const float*)d_in[1];
  const float* b1   = (const float*)d_in[2];
  const float* q1   = (const float*)d_in[3];
  const float* W3   = (const float*)d_in[4];
  const float* b3   = (const float*)d_in[5];
  const float* q2   = (const float*)d_in[6];
  const float* W5   = (const float*)d_in[7];
  const float* b5   = (const float*)d_in[8];
  const float* W6   = (const float*)d_in[9];
  const float* b6   = (const float*)d_in[10];
  const float* v    = (const float*)d_in[11];
  const float* W7   = (const float*)d_in[12];
  const float* b7   = (const float*)d_in[13];
  const float* W8   = (const float*)d_in[14];
  const float* b8   = (const float*)d_in[15];
  const float* bn1g = (const float*)d_in[16];
  const float* bn1b = (const float*)d_in[17];
  const float* bnEg = (const float*)d_in[18];
  const float* bnEb = (const float*)d_in[19];
  const float* lng  = (const float*)d_in[20];
  const float* lnb  = (const float*)d_in[21];
  const float* lab  = (const float*)d_in[22];
  float* out = (float*)d_out;
  float* ws  = (float*)d_ws;

  float* sgn   = ws;
  float* hq1   = ws + 819200L;
  float* hq2   = ws + 1638400L;
  float* pcat  = ws + 2457600L;    // [B][200]
  float* z5    = ws + 5734400L;
  float* z6    = ws + 7372800L;
  float* z7    = ws + 9011200L;
  float* z7b   = ws + 10649600L;
  float* h8    = ws + 12288000L;
  float* vvp   = ws + 13926400L;
  int*   iu    = (int*)(ws + 13931350L);
  int*   ju    = (int*)(ws + 13936300L);
  float* part  = ws + 13941250L;   // [1024][200]
  float* stats = ws + 14146050L;   // S1 Q1 S2 Q2 (50 ea) | S5 Q5 S6 Q6 S7 Q7 (100 ea)

  hipMemsetAsync(stats, 0, 800*sizeof(float), stream);
  k_prep<<<100, 128, 0, stream>>>(v, vvp, iu, ju);
  k_attn1<<<1024, 256, 0, stream>>>(x, W1, b1, q1, W3, b3, q2, sgn, hq1, hq2, part);
  k_red<<<200, 256, 0, stream>>>(part, stats);
  k_pool<<<16384, 128, 0, stream>>>(x, sgn, hq1, hq2, stats, q1, q2, bn1g, bn1b, pcat);
  k_z5<<<256, 256, 0, stream>>>(pcat, W5, b5, z5);
  k_colstats<<<256, 128, 0, stream>>>(z5, stats + 200, stats + 300);
  k_z6<<<256, 256, 0, stream>>>(z5, stats + 200, stats + 300, bnEg, bnEb, W6, b6, z6);
  k_cross<<<512, 256, 0, stream>>>(z5, stats + 200, stats + 300, bnEg, bnEb,
                                   W7, vvp, iu, ju, z7, z7b);
  k_colstats<<<256, 128, 0, stream>>>(z6, stats + 400, stats + 500);
  k_comb7<<<256, 128, 0, stream>>>(z7, z7b, b7, stats + 600, stats + 700);
  k_h8<<<256, 256, 0, stream>>>(z6, z7, stats + 400, stats + 500, stats + 600, stats + 700,
                                bnEg, bnEb, W8, b8, lng, lnb, h8);
  k_out<<<10240, 256, 0, stream>>>(h8, lab, out);
}